// Round 9
// baseline (199.043 us; speedup 1.0000x reference)
//
#include <hip/hip_runtime.h>

#define NB   8
#define ND   64
#define NP   1024
#define KDIM 128
#define HID  256
#define OUTD 256
#define CSC  2.885390081777927f   // 2*log2(e)

// E-trick: E = exp2(CSC*proj) = e^{2*proj};
// sigma = 1/(1 + Ed*Ep) = rcp(fma(Ed,Ep,1));  tanh(xd+xp) = 1 - 2*sigma.
// Ehp is stored TRANSPOSED: EhpT[b][h][j]  -> coalesced j-reads in k_scores.

// K1: projections + exp2. Block = 8 rows x 512 cols (W1|W2 side by side).
// Thread = 1 row x 16 cols: C=16 cols amortize each x ds_read -> LDS util
// 6/C = 37% (R7's C=1 was 6x oversubscribed = 43us). x staged in 4KB LDS;
// W read as 4x float4 per k (coalesced, L1/L2-resident).
// blocks [0,1024): protein (8 j each); [1024,1088): drug (8 i each).
__global__ __launch_bounds__(256) void k_proj(
    const float* __restrict__ Xd, const float* __restrict__ Xp,
    const float* __restrict__ Wd, const float* __restrict__ Wa,
    const float* __restrict__ Wp, const float* __restrict__ Wb,
    float* __restrict__ Ehd, float* __restrict__ Efd,
    float* __restrict__ EhpT, float* __restrict__ Efp) {
    int blk = blockIdx.x, t = threadIdx.x;
    const float *X, *W1, *W2;
    int row0, b, prot;
    if (blk < 1024) {
        b = blk >> 7;
        row0 = b * NP + (blk & 127) * 8;
        X = Xp; W1 = Wp; W2 = Wb; prot = 1;
    } else {
        int r = blk - 1024;
        b = r >> 3;
        row0 = b * ND + (r & 7) * 8;
        X = Xd; W1 = Wd; W2 = Wa; prot = 0;
    }
    __shared__ float4 xs[256];          // [8 rows][32 k4] = 4 KB
    xs[t] = ((const float4*)(X + (size_t)row0 * KDIM))[t];
    __syncthreads();

    int rg = t >> 5, cg = t & 31;       // row rg; cols c0..c0+15 of Wm
    const float* Wm = (cg < 16) ? W1 : W2;
    int c0 = (cg & 15) << 4;
    float acc[16];
#pragma unroll
    for (int q = 0; q < 16; ++q) acc[q] = 0.f;

    for (int k4 = 0; k4 < 32; ++k4) {
        float4 x = xs[(rg << 5) + k4];  // LDS b128 broadcast, reused x16
        const float* wb = Wm + ((k4 << 2) * HID + c0);
        {   const float4* wr = (const float4*)(wb);
            float4 w0 = wr[0], w1 = wr[1], w2 = wr[2], w3 = wr[3];
            acc[0]=fmaf(x.x,w0.x,acc[0]); acc[1]=fmaf(x.x,w0.y,acc[1]);
            acc[2]=fmaf(x.x,w0.z,acc[2]); acc[3]=fmaf(x.x,w0.w,acc[3]);
            acc[4]=fmaf(x.x,w1.x,acc[4]); acc[5]=fmaf(x.x,w1.y,acc[5]);
            acc[6]=fmaf(x.x,w1.z,acc[6]); acc[7]=fmaf(x.x,w1.w,acc[7]);
            acc[8]=fmaf(x.x,w2.x,acc[8]); acc[9]=fmaf(x.x,w2.y,acc[9]);
            acc[10]=fmaf(x.x,w2.z,acc[10]); acc[11]=fmaf(x.x,w2.w,acc[11]);
            acc[12]=fmaf(x.x,w3.x,acc[12]); acc[13]=fmaf(x.x,w3.y,acc[13]);
            acc[14]=fmaf(x.x,w3.z,acc[14]); acc[15]=fmaf(x.x,w3.w,acc[15]); }
        {   const float4* wr = (const float4*)(wb + HID);
            float4 w0 = wr[0], w1 = wr[1], w2 = wr[2], w3 = wr[3];
            acc[0]=fmaf(x.y,w0.x,acc[0]); acc[1]=fmaf(x.y,w0.y,acc[1]);
            acc[2]=fmaf(x.y,w0.z,acc[2]); acc[3]=fmaf(x.y,w0.w,acc[3]);
            acc[4]=fmaf(x.y,w1.x,acc[4]); acc[5]=fmaf(x.y,w1.y,acc[5]);
            acc[6]=fmaf(x.y,w1.z,acc[6]); acc[7]=fmaf(x.y,w1.w,acc[7]);
            acc[8]=fmaf(x.y,w2.x,acc[8]); acc[9]=fmaf(x.y,w2.y,acc[9]);
            acc[10]=fmaf(x.y,w2.z,acc[10]); acc[11]=fmaf(x.y,w2.w,acc[11]);
            acc[12]=fmaf(x.y,w3.x,acc[12]); acc[13]=fmaf(x.y,w3.y,acc[13]);
            acc[14]=fmaf(x.y,w3.z,acc[14]); acc[15]=fmaf(x.y,w3.w,acc[15]); }
        {   const float4* wr = (const float4*)(wb + 2 * HID);
            float4 w0 = wr[0], w1 = wr[1], w2 = wr[2], w3 = wr[3];
            acc[0]=fmaf(x.z,w0.x,acc[0]); acc[1]=fmaf(x.z,w0.y,acc[1]);
            acc[2]=fmaf(x.z,w0.z,acc[2]); acc[3]=fmaf(x.z,w0.w,acc[3]);
            acc[4]=fmaf(x.z,w1.x,acc[4]); acc[5]=fmaf(x.z,w1.y,acc[5]);
            acc[6]=fmaf(x.z,w1.z,acc[6]); acc[7]=fmaf(x.z,w1.w,acc[7]);
            acc[8]=fmaf(x.z,w2.x,acc[8]); acc[9]=fmaf(x.z,w2.y,acc[9]);
            acc[10]=fmaf(x.z,w2.z,acc[10]); acc[11]=fmaf(x.z,w2.w,acc[11]);
            acc[12]=fmaf(x.z,w3.x,acc[12]); acc[13]=fmaf(x.z,w3.y,acc[13]);
            acc[14]=fmaf(x.z,w3.z,acc[14]); acc[15]=fmaf(x.z,w3.w,acc[15]); }
        {   const float4* wr = (const float4*)(wb + 3 * HID);
            float4 w0 = wr[0], w1 = wr[1], w2 = wr[2], w3 = wr[3];
            acc[0]=fmaf(x.w,w0.x,acc[0]); acc[1]=fmaf(x.w,w0.y,acc[1]);
            acc[2]=fmaf(x.w,w0.z,acc[2]); acc[3]=fmaf(x.w,w0.w,acc[3]);
            acc[4]=fmaf(x.w,w1.x,acc[4]); acc[5]=fmaf(x.w,w1.y,acc[5]);
            acc[6]=fmaf(x.w,w1.z,acc[6]); acc[7]=fmaf(x.w,w1.w,acc[7]);
            acc[8]=fmaf(x.w,w2.x,acc[8]); acc[9]=fmaf(x.w,w2.y,acc[9]);
            acc[10]=fmaf(x.w,w2.z,acc[10]); acc[11]=fmaf(x.w,w2.w,acc[11]);
            acc[12]=fmaf(x.w,w3.x,acc[12]); acc[13]=fmaf(x.w,w3.y,acc[13]);
            acc[14]=fmaf(x.w,w3.z,acc[14]); acc[15]=fmaf(x.w,w3.w,acc[15]); }
    }

    float e[16];
#pragma unroll
    for (int q = 0; q < 16; ++q)
        e[q] = __builtin_amdgcn_exp2f(acc[q] * CSC);

    if (prot && cg < 16) {
        // EhpT[b][c0+q][j]: 16-way scatter, stride NP (32B/line used)
        int j = (blk & 127) * 8 + rg;
        float* dst = EhpT + ((size_t)((b << 8) + c0)) * NP + j;
#pragma unroll
        for (int q = 0; q < 16; ++q) dst[q * NP] = e[q];
    } else {
        float* O = prot ? Efp : ((cg < 16) ? Ehd : Efd);
        float4* dst = (float4*)(O + (size_t)(row0 + rg) * HID + c0);
        dst[0] = make_float4(e[0], e[1], e[2], e[3]);
        dst[1] = make_float4(e[4], e[5], e[6], e[7]);
        dst[2] = make_float4(e[8], e[9], e[10], e[11]);
        dst[3] = make_float4(e[12], e[13], e[14], e[15]);
    }
}

// K2: shifted scores S[b,i,j] = -2 * sum_h w_h * rcp(1 + Ehd*EhpT).
// No LDS, no barrier. Block = 8 i x 64 j; thread: jg = t&63 (coalesced j),
// iq = t>>6 wave-uniform -> Ehd/w loads are scalar. grid = 8*8*16 = 1024.
__global__ __launch_bounds__(256) void k_scores(
    const float* __restrict__ Ehd, const float* __restrict__ EhpT,
    const float* __restrict__ wsc, float* __restrict__ S) {
    int blk = blockIdx.x;
    int b = blk >> 7, r = blk & 127, it = r >> 4, jt = r & 15;
    int i0 = it * 8, j0 = jt * 64;
    int t = threadIdx.x;
    int jg = t & 63, iq = t >> 6;
    int i = i0 + iq * 2;
    const float4* h0v4 = (const float4*)(Ehd + ((b * ND + i) << 8));
    const float4* h1v4 = (const float4*)(Ehd + ((b * ND + i + 1) << 8));
    const float4* w4   = (const float4*)wsc;
    const float* pT = EhpT + ((size_t)(b << 8)) * NP + j0 + jg;
    float acc0 = 0.f, acc1 = 0.f;
#pragma unroll 4
    for (int h4 = 0; h4 < 64; ++h4) {
        float4 h0 = h0v4[h4];           // wave-uniform (scalar)
        float4 h1 = h1v4[h4];
        float4 wv = w4[h4];
        float p0 = pT[(h4 * 4 + 0) * NP];   // coalesced 256B
        float p1 = pT[(h4 * 4 + 1) * NP];
        float p2 = pT[(h4 * 4 + 2) * NP];
        float p3 = pT[(h4 * 4 + 3) * NP];
        acc0 = fmaf(wv.x, __builtin_amdgcn_rcpf(fmaf(h0.x, p0, 1.f)), acc0);
        acc0 = fmaf(wv.y, __builtin_amdgcn_rcpf(fmaf(h0.y, p1, 1.f)), acc0);
        acc0 = fmaf(wv.z, __builtin_amdgcn_rcpf(fmaf(h0.z, p2, 1.f)), acc0);
        acc0 = fmaf(wv.w, __builtin_amdgcn_rcpf(fmaf(h0.w, p3, 1.f)), acc0);
        acc1 = fmaf(wv.x, __builtin_amdgcn_rcpf(fmaf(h1.x, p0, 1.f)), acc1);
        acc1 = fmaf(wv.y, __builtin_amdgcn_rcpf(fmaf(h1.y, p1, 1.f)), acc1);
        acc1 = fmaf(wv.z, __builtin_amdgcn_rcpf(fmaf(h1.z, p2, 1.f)), acc1);
        acc1 = fmaf(wv.w, __builtin_amdgcn_rcpf(fmaf(h1.w, p3, 1.f)), acc1);
    }
    int base = ((b * ND + i) << 10) + j0 + jg;
    S[base]        = -2.f * acc0;
    S[base + 1024] = -2.f * acc1;
}

// K3: softmax over j per (b,i) row, in place; writes A2 = -2*A.
// No max pass: |S| <= 2*sum|w| <= 32, exp2 arg <= ~46 -> fp32-safe.
__global__ __launch_bounds__(256) void k_softmax(float* __restrict__ S) {
    int row = blockIdx.x;
    int t = threadIdx.x;
    float* Srow = S + (row << 10);
    float4 v = ((float4*)Srow)[t];
    const float L2E = 1.4426950408889634f;
    v.x = __builtin_amdgcn_exp2f(v.x * L2E);
    v.y = __builtin_amdgcn_exp2f(v.y * L2E);
    v.z = __builtin_amdgcn_exp2f(v.z * L2E);
    v.w = __builtin_amdgcn_exp2f(v.w * L2E);
    float s4 = (v.x + v.y) + (v.z + v.w);
#pragma unroll
    for (int off = 32; off > 0; off >>= 1) s4 += __shfl_xor(s4, off, 64);
    __shared__ float wsum[4];
    if ((t & 63) == 0) wsum[t >> 6] = s4;
    __syncthreads();
    float tot = (wsum[0] + wsum[1]) + (wsum[2] + wsum[3]);
    float sneg = -2.0f * __builtin_amdgcn_rcpf(tot);   // A2 = -2*A
    v.x *= sneg; v.y *= sneg; v.z *= sneg; v.w *= sneg;
    ((float4*)Srow)[t] = v;
}

// K4: partial[blk][o] = sum_{i in 32, j in 16} A2 * rcp(1 + Efd*Efp).
// (X_int = 64 + sum of all partials, since sum_j A = 1 per i.)
// Efd from L2 (coalesced 1 KB/wave loads); LDS = 6 KB. grid = 1024.
__global__ __launch_bounds__(256) void k_facc(
    const float* __restrict__ Efd, const float* __restrict__ Efp,
    const float* __restrict__ A2, float* __restrict__ part) {
    int blk = blockIdx.x;
    int b = blk >> 7, rr = blk & 127, ih = rr >> 6, jt = rr & 63;
    int i0 = ih * 32, j0 = jt * 16;
    int t = threadIdx.x;
    __shared__ float4 as4[32 * 4];    // 2 KB  (A2 tile [32 i][16 j])
    __shared__ float4 red[256];       // 4 KB
    if (t < 128) {
        int ii = t >> 2, jq = t & 3;
        as4[t] = ((const float4*)A2)[((b * ND + i0 + ii) << 8) + (j0 >> 2) + jq];
    }
    __syncthreads();

    int o4 = t & 63, jq = t >> 6;
    const float4* fdg = (const float4*)(Efd + ((b * ND + i0) << 8));
    const float4* fpg = (const float4*)(Efp + ((b * NP + j0 + (jq << 2)) << 8));
    float4 fv0 = fpg[o4], fv1 = fpg[64 + o4], fv2 = fpg[128 + o4], fv3 = fpg[192 + o4];
    float4 acc = {0.f, 0.f, 0.f, 0.f};
    for (int i = 0; i < 32; ++i) {
        float4 dv = fdg[(i << 6) + o4];   // global, coalesced, L2-hit
        float4 a  = as4[(i << 2) + jq];
        acc.x = fmaf(a.x, __builtin_amdgcn_rcpf(fmaf(dv.x, fv0.x, 1.f)), acc.x);
        acc.y = fmaf(a.x, __builtin_amdgcn_rcpf(fmaf(dv.y, fv0.y, 1.f)), acc.y);
        acc.z = fmaf(a.x, __builtin_amdgcn_rcpf(fmaf(dv.z, fv0.z, 1.f)), acc.z);
        acc.w = fmaf(a.x, __builtin_amdgcn_rcpf(fmaf(dv.w, fv0.w, 1.f)), acc.w);
        acc.x = fmaf(a.y, __builtin_amdgcn_rcpf(fmaf(dv.x, fv1.x, 1.f)), acc.x);
        acc.y = fmaf(a.y, __builtin_amdgcn_rcpf(fmaf(dv.y, fv1.y, 1.f)), acc.y);
        acc.z = fmaf(a.y, __builtin_amdgcn_rcpf(fmaf(dv.z, fv1.z, 1.f)), acc.z);
        acc.w = fmaf(a.y, __builtin_amdgcn_rcpf(fmaf(dv.w, fv1.w, 1.f)), acc.w);
        acc.x = fmaf(a.z, __builtin_amdgcn_rcpf(fmaf(dv.x, fv2.x, 1.f)), acc.x);
        acc.y = fmaf(a.z, __builtin_amdgcn_rcpf(fmaf(dv.y, fv2.y, 1.f)), acc.y);
        acc.z = fmaf(a.z, __builtin_amdgcn_rcpf(fmaf(dv.z, fv2.z, 1.f)), acc.z);
        acc.w = fmaf(a.z, __builtin_amdgcn_rcpf(fmaf(dv.w, fv2.w, 1.f)), acc.w);
        acc.x = fmaf(a.w, __builtin_amdgcn_rcpf(fmaf(dv.x, fv3.x, 1.f)), acc.x);
        acc.y = fmaf(a.w, __builtin_amdgcn_rcpf(fmaf(dv.y, fv3.y, 1.f)), acc.y);
        acc.z = fmaf(a.w, __builtin_amdgcn_rcpf(fmaf(dv.z, fv3.z, 1.f)), acc.z);
        acc.w = fmaf(a.w, __builtin_amdgcn_rcpf(fmaf(dv.w, fv3.w, 1.f)), acc.w);
    }
    red[t] = acc; __syncthreads();
    if (t < 64) {
        float4 r0 = red[t], r1 = red[64 + t], r2 = red[128 + t], r3 = red[192 + t];
        float4 s;
        s.x = (r0.x + r1.x) + (r2.x + r3.x);
        s.y = (r0.y + r1.y) + (r2.y + r3.y);
        s.z = (r0.z + r1.z) + (r2.z + r3.z);
        s.w = (r0.w + r1.w) + (r2.w + r3.w);
        ((float4*)part)[(blk << 6) + t] = s;
    }
}

// K5: out[b][o] = 64 + sum over 128 partials. 64 blocks (8b x 8 o-chunks).
__global__ __launch_bounds__(256) void k_reduce(
    const float* __restrict__ part, float* __restrict__ out) {
    int b = blockIdx.x >> 3, oc = blockIdx.x & 7;
    int t = threadIdx.x;
    int o = oc * 32 + (t & 31), q0 = t >> 5;
    float s = 0.f;
#pragma unroll
    for (int k = 0; k < 16; ++k)
        s += part[((b * 128 + q0 + k * 8) << 8) + o];
    __shared__ float red[256];
    red[t] = s; __syncthreads();
    for (int st = 128; st >= 32; st >>= 1) {
        if (t < st) red[t] += red[t + st];
        __syncthreads();
    }
    if (t < 32) out[(b << 8) + oc * 32 + t] = 64.0f + red[t];
}

extern "C" void kernel_launch(void* const* d_in, const int* in_sizes, int n_in,
                              void* d_out, int out_size, void* d_ws, size_t ws_size,
                              hipStream_t stream) {
    const float* Xd  = (const float*)d_in[0];
    const float* Xp  = (const float*)d_in[1];
    const float* Wd  = (const float*)d_in[2];
    const float* Wp  = (const float*)d_in[3];
    const float* Wa  = (const float*)d_in[4];
    const float* Wb  = (const float*)d_in[5];
    const float* wsc = (const float*)d_in[6];
    float* out = (float*)d_out;

    float* ws = (float*)d_ws;
    float* Ehd  = ws;                       // 131072
    float* Efd  = Ehd + NB * ND * HID;      // 131072
    float* EhpT = Efd + NB * ND * OUTD;     // 2097152  (transposed [b][h][j])
    float* Efp  = EhpT + NB * NP * HID;     // 2097152
    float* S    = Efp + NB * NP * OUTD;     // 524288
    float* part = EhpT;                     // overlay: EhpT dead after k_scores

    k_proj   <<<1088, 256, 0, stream>>>(Xd, Xp, Wd, Wa, Wp, Wb, Ehd, Efd, EhpT, Efp);
    k_scores <<<1024, 256, 0, stream>>>(Ehd, EhpT, wsc, S);
    k_softmax<<<NB * ND, 256, 0, stream>>>(S);
    k_facc   <<<NB * 128, 256, 0, stream>>>(Efd, Efp, S, part);
    k_reduce <<<64, 256, 0, stream>>>(part, out);
}

// Round 10
// 104.789 us; speedup vs baseline: 1.8995x; 1.8995x over previous
//
#include <hip/hip_runtime.h>

#define NB   8
#define ND   64
#define NP   1024
#define KDIM 128
#define HID  256
#define OUTD 256
#define CSC  2.885390081777927f   // 2*log2(e)

// E-trick: E = exp2(CSC*proj) = e^{2*proj};
// sigma = 1/(1 + Ed*Ep) = rcp(fma(Ed,Ep,1));  tanh(xd+xp) = 1 - 2*sigma.
// Ehp is stored TRANSPOSED: EhpT[b][h][j]  -> coalesced j-reads in k_scores.

// K1: projection GEMM, register-tiled R=4 rows x C=8 cols per thread, no LDS.
// x: same-address-per-32-lane float4 broadcast loads (L1 1-transaction);
// w: 2 coalesced float4 per k; 12 VMEM in flight per 256 FMA-cycles.
// Block = 32 rows x 256 cols (ONE W matrix). grid = 512 protein + 32 drug.
__global__ __launch_bounds__(256) void k_proj(
    const float* __restrict__ Xd, const float* __restrict__ Xp,
    const float* __restrict__ Wd, const float* __restrict__ Wa,
    const float* __restrict__ Wp, const float* __restrict__ Wb,
    float* __restrict__ Ehd, float* __restrict__ Efd,
    float* __restrict__ EhpT, float* __restrict__ Efp) {
    int blk = blockIdx.x, t = threadIdx.x;
    const float *X, *W;
    int row0, b, kind, jloc = 0;        // kind: 0=Ehd 1=Efd 2=EhpT 3=Efp
    if (blk < 512) {
        b = blk >> 6;
        int r = blk & 63, mat = r & 1, tile = r >> 1;   // tile 0..31
        row0 = b * NP + tile * 32; jloc = tile * 32;
        X = Xp; W = mat ? Wb : Wp; kind = mat ? 3 : 2;
    } else {
        int r = blk - 512;
        b = r >> 2;
        int mat = r & 1, tile = (r >> 1) & 1;
        row0 = b * ND + tile * 32;
        X = Xd; W = mat ? Wa : Wd; kind = mat ? 1 : 0;
    }
    int rg = t >> 5, cg = t & 31;       // rows rg*4..+3; cols cg*8..+7
    int c0 = cg << 3;
    const float* Xr = X + (size_t)(row0 + (rg << 2)) * KDIM;

    float acc[4][8];
#pragma unroll
    for (int r = 0; r < 4; ++r)
#pragma unroll
        for (int c = 0; c < 8; ++c) acc[r][c] = 0.f;

#define FMA8(xs, kk)                                                         \
    do {                                                                     \
        acc[r_][0] = fmaf(xs, wv[kk][0].x, acc[r_][0]);                      \
        acc[r_][1] = fmaf(xs, wv[kk][0].y, acc[r_][1]);                      \
        acc[r_][2] = fmaf(xs, wv[kk][0].z, acc[r_][2]);                      \
        acc[r_][3] = fmaf(xs, wv[kk][0].w, acc[r_][3]);                      \
        acc[r_][4] = fmaf(xs, wv[kk][1].x, acc[r_][4]);                      \
        acc[r_][5] = fmaf(xs, wv[kk][1].y, acc[r_][5]);                      \
        acc[r_][6] = fmaf(xs, wv[kk][1].z, acc[r_][6]);                      \
        acc[r_][7] = fmaf(xs, wv[kk][1].w, acc[r_][7]);                      \
    } while (0)

    for (int k4 = 0; k4 < 32; ++k4) {
        int k = k4 << 2;
        float4 xv[4];
#pragma unroll
        for (int r = 0; r < 4; ++r)
            xv[r] = *(const float4*)(Xr + r * KDIM + k);   // broadcast/32 lanes
        float4 wv[4][2];
#pragma unroll
        for (int kk = 0; kk < 4; ++kk) {
            const float4* wr = (const float4*)(W + (size_t)(k + kk) * HID + c0);
            wv[kk][0] = wr[0];
            wv[kk][1] = wr[1];
        }
#pragma unroll
        for (int r_ = 0; r_ < 4; ++r_) {
            FMA8(xv[r_].x, 0);
            FMA8(xv[r_].y, 1);
            FMA8(xv[r_].z, 2);
            FMA8(xv[r_].w, 3);
        }
    }
#undef FMA8

    float e[4][8];
#pragma unroll
    for (int r = 0; r < 4; ++r)
#pragma unroll
        for (int c = 0; c < 8; ++c)
            e[r][c] = __builtin_amdgcn_exp2f(acc[r][c] * CSC);

    if (kind == 2) {
        // EhpT[b][c0+c][jloc + rg*4 .. +3]: one float4 per col (j-contiguous)
#pragma unroll
        for (int c = 0; c < 8; ++c) {
            float4 v = make_float4(e[0][c], e[1][c], e[2][c], e[3][c]);
            *(float4*)(EhpT + ((size_t)((b << 8) + c0 + c)) * NP + jloc + (rg << 2)) = v;
        }
    } else {
        float* O = (kind == 0) ? Ehd : (kind == 1) ? Efd : Efp;
#pragma unroll
        for (int r = 0; r < 4; ++r) {
            float4* dst = (float4*)(O + (size_t)(row0 + (rg << 2) + r) * HID + c0);
            dst[0] = make_float4(e[r][0], e[r][1], e[r][2], e[r][3]);
            dst[1] = make_float4(e[r][4], e[r][5], e[r][6], e[r][7]);
        }
    }
}

// K2: shifted scores S[b,i,j] = -2 * sum_h w_h * rcp(1 + Ehd*EhpT).
// No LDS, no barrier. Block = 8 i x 64 j; thread: jg = t&63 (coalesced j),
// iq = t>>6 wave-uniform -> Ehd/w loads are scalar. grid = 8*8*16 = 1024.
__global__ __launch_bounds__(256) void k_scores(
    const float* __restrict__ Ehd, const float* __restrict__ EhpT,
    const float* __restrict__ wsc, float* __restrict__ S) {
    int blk = blockIdx.x;
    int b = blk >> 7, r = blk & 127, it = r >> 4, jt = r & 15;
    int i0 = it * 8, j0 = jt * 64;
    int t = threadIdx.x;
    int jg = t & 63, iq = t >> 6;
    int i = i0 + iq * 2;
    const float4* h0v4 = (const float4*)(Ehd + ((b * ND + i) << 8));
    const float4* h1v4 = (const float4*)(Ehd + ((b * ND + i + 1) << 8));
    const float4* w4   = (const float4*)wsc;
    const float* pT = EhpT + ((size_t)(b << 8)) * NP + j0 + jg;
    float acc0 = 0.f, acc1 = 0.f;
#pragma unroll 4
    for (int h4 = 0; h4 < 64; ++h4) {
        float4 h0 = h0v4[h4];           // wave-uniform (scalar)
        float4 h1 = h1v4[h4];
        float4 wv = w4[h4];
        float p0 = pT[(h4 * 4 + 0) * NP];   // coalesced 256B
        float p1 = pT[(h4 * 4 + 1) * NP];
        float p2 = pT[(h4 * 4 + 2) * NP];
        float p3 = pT[(h4 * 4 + 3) * NP];
        acc0 = fmaf(wv.x, __builtin_amdgcn_rcpf(fmaf(h0.x, p0, 1.f)), acc0);
        acc0 = fmaf(wv.y, __builtin_amdgcn_rcpf(fmaf(h0.y, p1, 1.f)), acc0);
        acc0 = fmaf(wv.z, __builtin_amdgcn_rcpf(fmaf(h0.z, p2, 1.f)), acc0);
        acc0 = fmaf(wv.w, __builtin_amdgcn_rcpf(fmaf(h0.w, p3, 1.f)), acc0);
        acc1 = fmaf(wv.x, __builtin_amdgcn_rcpf(fmaf(h1.x, p0, 1.f)), acc1);
        acc1 = fmaf(wv.y, __builtin_amdgcn_rcpf(fmaf(h1.y, p1, 1.f)), acc1);
        acc1 = fmaf(wv.z, __builtin_amdgcn_rcpf(fmaf(h1.z, p2, 1.f)), acc1);
        acc1 = fmaf(wv.w, __builtin_amdgcn_rcpf(fmaf(h1.w, p3, 1.f)), acc1);
    }
    int base = ((b * ND + i) << 10) + j0 + jg;
    S[base]        = -2.f * acc0;
    S[base + 1024] = -2.f * acc1;
}

// K3: softmax over j per (b,i) row, in place; writes A2 = -2*A.
// No max pass: |S| <= 2*sum|w| <= 32, exp2 arg <= ~46 -> fp32-safe.
__global__ __launch_bounds__(256) void k_softmax(float* __restrict__ S) {
    int row = blockIdx.x;
    int t = threadIdx.x;
    float* Srow = S + (row << 10);
    float4 v = ((float4*)Srow)[t];
    const float L2E = 1.4426950408889634f;
    v.x = __builtin_amdgcn_exp2f(v.x * L2E);
    v.y = __builtin_amdgcn_exp2f(v.y * L2E);
    v.z = __builtin_amdgcn_exp2f(v.z * L2E);
    v.w = __builtin_amdgcn_exp2f(v.w * L2E);
    float s4 = (v.x + v.y) + (v.z + v.w);
#pragma unroll
    for (int off = 32; off > 0; off >>= 1) s4 += __shfl_xor(s4, off, 64);
    __shared__ float wsum[4];
    if ((t & 63) == 0) wsum[t >> 6] = s4;
    __syncthreads();
    float tot = (wsum[0] + wsum[1]) + (wsum[2] + wsum[3]);
    float sneg = -2.0f * __builtin_amdgcn_rcpf(tot);   // A2 = -2*A
    v.x *= sneg; v.y *= sneg; v.z *= sneg; v.w *= sneg;
    ((float4*)Srow)[t] = v;
}

// K4: partial[blk][o] = sum_{i in 32, j in 16} A2 * rcp(1 + Efd*Efp).
// (X_int = 64 + sum of all partials, since sum_j A = 1 per i.)
// Efd from L2 (coalesced 1 KB/wave loads); LDS = 6 KB. grid = 1024.
__global__ __launch_bounds__(256) void k_facc(
    const float* __restrict__ Efd, const float* __restrict__ Efp,
    const float* __restrict__ A2, float* __restrict__ part) {
    int blk = blockIdx.x;
    int b = blk >> 7, rr = blk & 127, ih = rr >> 6, jt = rr & 63;
    int i0 = ih * 32, j0 = jt * 16;
    int t = threadIdx.x;
    __shared__ float4 as4[32 * 4];    // 2 KB  (A2 tile [32 i][16 j])
    __shared__ float4 red[256];       // 4 KB
    if (t < 128) {
        int ii = t >> 2, jq = t & 3;
        as4[t] = ((const float4*)A2)[((b * ND + i0 + ii) << 8) + (j0 >> 2) + jq];
    }
    __syncthreads();

    int o4 = t & 63, jq = t >> 6;
    const float4* fdg = (const float4*)(Efd + ((b * ND + i0) << 8));
    const float4* fpg = (const float4*)(Efp + ((b * NP + j0 + (jq << 2)) << 8));
    float4 fv0 = fpg[o4], fv1 = fpg[64 + o4], fv2 = fpg[128 + o4], fv3 = fpg[192 + o4];
    float4 acc = {0.f, 0.f, 0.f, 0.f};
    for (int i = 0; i < 32; ++i) {
        float4 dv = fdg[(i << 6) + o4];   // global, coalesced, L2-hit
        float4 a  = as4[(i << 2) + jq];
        acc.x = fmaf(a.x, __builtin_amdgcn_rcpf(fmaf(dv.x, fv0.x, 1.f)), acc.x);
        acc.y = fmaf(a.x, __builtin_amdgcn_rcpf(fmaf(dv.y, fv0.y, 1.f)), acc.y);
        acc.z = fmaf(a.x, __builtin_amdgcn_rcpf(fmaf(dv.z, fv0.z, 1.f)), acc.z);
        acc.w = fmaf(a.x, __builtin_amdgcn_rcpf(fmaf(dv.w, fv0.w, 1.f)), acc.w);
        acc.x = fmaf(a.y, __builtin_amdgcn_rcpf(fmaf(dv.x, fv1.x, 1.f)), acc.x);
        acc.y = fmaf(a.y, __builtin_amdgcn_rcpf(fmaf(dv.y, fv1.y, 1.f)), acc.y);
        acc.z = fmaf(a.y, __builtin_amdgcn_rcpf(fmaf(dv.z, fv1.z, 1.f)), acc.z);
        acc.w = fmaf(a.y, __builtin_amdgcn_rcpf(fmaf(dv.w, fv1.w, 1.f)), acc.w);
        acc.x = fmaf(a.z, __builtin_amdgcn_rcpf(fmaf(dv.x, fv2.x, 1.f)), acc.x);
        acc.y = fmaf(a.z, __builtin_amdgcn_rcpf(fmaf(dv.y, fv2.y, 1.f)), acc.y);
        acc.z = fmaf(a.z, __builtin_amdgcn_rcpf(fmaf(dv.z, fv2.z, 1.f)), acc.z);
        acc.w = fmaf(a.z, __builtin_amdgcn_rcpf(fmaf(dv.w, fv2.w, 1.f)), acc.w);
        acc.x = fmaf(a.w, __builtin_amdgcn_rcpf(fmaf(dv.x, fv3.x, 1.f)), acc.x);
        acc.y = fmaf(a.w, __builtin_amdgcn_rcpf(fmaf(dv.y, fv3.y, 1.f)), acc.y);
        acc.z = fmaf(a.w, __builtin_amdgcn_rcpf(fmaf(dv.z, fv3.z, 1.f)), acc.z);
        acc.w = fmaf(a.w, __builtin_amdgcn_rcpf(fmaf(dv.w, fv3.w, 1.f)), acc.w);
    }
    red[t] = acc; __syncthreads();
    if (t < 64) {
        float4 r0 = red[t], r1 = red[64 + t], r2 = red[128 + t], r3 = red[192 + t];
        float4 s;
        s.x = (r0.x + r1.x) + (r2.x + r3.x);
        s.y = (r0.y + r1.y) + (r2.y + r3.y);
        s.z = (r0.z + r1.z) + (r2.z + r3.z);
        s.w = (r0.w + r1.w) + (r2.w + r3.w);
        ((float4*)part)[(blk << 6) + t] = s;
    }
}

// K5: out[b][o] = 64 + sum over 128 partials. 64 blocks (8b x 8 o-chunks).
__global__ __launch_bounds__(256) void k_reduce(
    const float* __restrict__ part, float* __restrict__ out) {
    int b = blockIdx.x >> 3, oc = blockIdx.x & 7;
    int t = threadIdx.x;
    int o = oc * 32 + (t & 31), q0 = t >> 5;
    float s = 0.f;
#pragma unroll
    for (int k = 0; k < 16; ++k)
        s += part[((b * 128 + q0 + k * 8) << 8) + o];
    __shared__ float red[256];
    red[t] = s; __syncthreads();
    for (int st = 128; st >= 32; st >>= 1) {
        if (t < st) red[t] += red[t + st];
        __syncthreads();
    }
    if (t < 32) out[(b << 8) + oc * 32 + t] = 64.0f + red[t];
}

extern "C" void kernel_launch(void* const* d_in, const int* in_sizes, int n_in,
                              void* d_out, int out_size, void* d_ws, size_t ws_size,
                              hipStream_t stream) {
    const float* Xd  = (const float*)d_in[0];
    const float* Xp  = (const float*)d_in[1];
    const float* Wd  = (const float*)d_in[2];
    const float* Wp  = (const float*)d_in[3];
    const float* Wa  = (const float*)d_in[4];
    const float* Wb  = (const float*)d_in[5];
    const float* wsc = (const float*)d_in[6];
    float* out = (float*)d_out;

    float* ws = (float*)d_ws;
    float* Ehd  = ws;                       // 131072
    float* Efd  = Ehd + NB * ND * HID;      // 131072
    float* EhpT = Efd + NB * ND * OUTD;     // 2097152  (transposed [b][h][j])
    float* Efp  = EhpT + NB * NP * HID;     // 2097152
    float* S    = Efp + NB * NP * OUTD;     // 524288
    float* part = EhpT;                     // overlay: EhpT dead after k_scores

    k_proj   <<<544, 256, 0, stream>>>(Xd, Xp, Wd, Wa, Wp, Wb, Ehd, Efd, EhpT, Efp);
    k_scores <<<1024, 256, 0, stream>>>(Ehd, EhpT, wsc, S);
    k_softmax<<<NB * ND, 256, 0, stream>>>(S);
    k_facc   <<<NB * 128, 256, 0, stream>>>(Efd, Efp, S, part);
    k_reduce <<<64, 256, 0, stream>>>(part, out);
}

// Round 12
// 104.071 us; speedup vs baseline: 1.9126x; 1.0069x over previous
//
#include <hip/hip_runtime.h>

#define NB   8
#define ND   64
#define NP   1024
#define KDIM 128
#define HID  256
#define OUTD 256
#define CSC  2.885390081777927f   // 2*log2(e)

// E-trick: E = exp2(CSC*proj) = e^{2*proj};
// sigma = 1/(1 + Ed*Ep) = rcp(fma(Ed,Ep,1));  tanh(xd+xp) = 1 - 2*sigma.
// EhpT stored transposed [b][h][j] -> coalesced j-reads in k_scores.

// K1: projection GEMM, 2-deep software pipeline pinned with sched_barrier(0).
// R10 failure: compiler sank all loads to point-of-use (VGPR 36 -> serial
// 200cy stalls, 56us). Named A/B load sets + sched_barrier force both sets
// live (~110 VGPR) so 10 loads fly under 64 FMAs.
// Block = 16 rows x 256 cols of ONE W. Thread = 2 rows x 8 cols.
// grid: protein 8b*64tiles*2mats = 1024; drug 8b*4tiles*2mats = 64.
__global__ __launch_bounds__(256) void k_proj(
    const float* __restrict__ Xd, const float* __restrict__ Xp,
    const float* __restrict__ Wd, const float* __restrict__ Wa,
    const float* __restrict__ Wp, const float* __restrict__ Wb,
    float* __restrict__ Ehd, float* __restrict__ Efd,
    float* __restrict__ EhpT, float* __restrict__ Efp) {
    int blk = blockIdx.x, t = threadIdx.x;
    const float *X, *W;
    int row0, b, kind, jloc = 0;        // kind: 0=Ehd 1=Efd 2=EhpT 3=Efp
    if (blk < 1024) {
        b = blk >> 7;
        int r = blk & 127, tile = r >> 1, mat = r & 1;
        row0 = b * NP + tile * 16; jloc = tile * 16;
        X = Xp; W = mat ? Wb : Wp; kind = mat ? 3 : 2;
    } else {
        int r2 = blk - 1024;
        b = r2 >> 3;
        int rr = r2 & 7, tile = rr >> 1, mat = rr & 1;
        row0 = b * ND + tile * 16;
        X = Xd; W = mat ? Wa : Wd; kind = mat ? 1 : 0;
    }
    int rg = t >> 5, cg = t & 31;       // rows rg*2..+1; cols cg*8..+7
    int c0 = cg << 3;
    const float* Xr = X + (size_t)(row0 + (rg << 1)) * KDIM;
    const float* Wc = W + c0;

    float acc[2][8];
#pragma unroll
    for (int r = 0; r < 2; ++r)
#pragma unroll
        for (int c = 0; c < 8; ++c) acc[r][c] = 0.f;

    float4 xA0, xA1, wA00, wA01, wA10, wA11, wA20, wA21, wA30, wA31;
    float4 xB0, xB1, wB00, wB01, wB10, wB11, wB20, wB21, wB30, wB31;

#define LOADSET(S, k4)                                                        \
    do {                                                                      \
        const float* xp_ = Xr + ((k4) << 2);                                  \
        x##S##0 = *(const float4*)(xp_);                                      \
        x##S##1 = *(const float4*)(xp_ + KDIM);                               \
        const float* wp_ = Wc + (size_t)((k4) << 2) * HID;                    \
        w##S##00 = *(const float4*)(wp_);                                     \
        w##S##01 = *(const float4*)(wp_ + 4);                                 \
        w##S##10 = *(const float4*)(wp_ + HID);                               \
        w##S##11 = *(const float4*)(wp_ + HID + 4);                           \
        w##S##20 = *(const float4*)(wp_ + 2 * HID);                           \
        w##S##21 = *(const float4*)(wp_ + 2 * HID + 4);                       \
        w##S##30 = *(const float4*)(wp_ + 3 * HID);                           \
        w##S##31 = *(const float4*)(wp_ + 3 * HID + 4);                       \
    } while (0)

#define FMA16(x0s, x1s, w0, w1)                                               \
    do {                                                                      \
        acc[0][0] = fmaf(x0s, w0.x, acc[0][0]);                               \
        acc[0][1] = fmaf(x0s, w0.y, acc[0][1]);                               \
        acc[0][2] = fmaf(x0s, w0.z, acc[0][2]);                               \
        acc[0][3] = fmaf(x0s, w0.w, acc[0][3]);                               \
        acc[0][4] = fmaf(x0s, w1.x, acc[0][4]);                               \
        acc[0][5] = fmaf(x0s, w1.y, acc[0][5]);                               \
        acc[0][6] = fmaf(x0s, w1.z, acc[0][6]);                               \
        acc[0][7] = fmaf(x0s, w1.w, acc[0][7]);                               \
        acc[1][0] = fmaf(x1s, w0.x, acc[1][0]);                               \
        acc[1][1] = fmaf(x1s, w0.y, acc[1][1]);                               \
        acc[1][2] = fmaf(x1s, w0.z, acc[1][2]);                               \
        acc[1][3] = fmaf(x1s, w0.w, acc[1][3]);                               \
        acc[1][4] = fmaf(x1s, w1.x, acc[1][4]);                               \
        acc[1][5] = fmaf(x1s, w1.y, acc[1][5]);                               \
        acc[1][6] = fmaf(x1s, w1.z, acc[1][6]);                               \
        acc[1][7] = fmaf(x1s, w1.w, acc[1][7]);                               \
    } while (0)

// NOTE: copy x-vecs to locals first — pasting x##S##0 directly against ".x"
// would lex "0.x" as one pp-number token and break (R11 compile failure).
#define FMASET(S)                                                             \
    do {                                                                      \
        float4 x0_ = x##S##0, x1_ = x##S##1;                                  \
        FMA16(x0_.x, x1_.x, w##S##00, w##S##01);                              \
        FMA16(x0_.y, x1_.y, w##S##10, w##S##11);                              \
        FMA16(x0_.z, x1_.z, w##S##20, w##S##21);                              \
        FMA16(x0_.w, x1_.w, w##S##30, w##S##31);                              \
    } while (0)

    LOADSET(A, 0);
    for (int k8 = 0; k8 < 15; ++k8) {
        LOADSET(B, 2 * k8 + 1);                 // prefetch B
        __builtin_amdgcn_sched_barrier(0);      // pin: B issued before A-FMAs
        FMASET(A);
        LOADSET(A, 2 * k8 + 2);                 // prefetch next A
        __builtin_amdgcn_sched_barrier(0);
        FMASET(B);
    }
    LOADSET(B, 31);
    __builtin_amdgcn_sched_barrier(0);
    FMASET(A);
    __builtin_amdgcn_sched_barrier(0);
    FMASET(B);

#undef LOADSET
#undef FMA16
#undef FMASET

    float e[2][8];
#pragma unroll
    for (int r = 0; r < 2; ++r)
#pragma unroll
        for (int c = 0; c < 8; ++c)
            e[r][c] = __builtin_amdgcn_exp2f(acc[r][c] * CSC);

    if (kind == 2) {
        // EhpT[b][c0+c][jloc + rg*2 .. +1]: float2 per col
#pragma unroll
        for (int c = 0; c < 8; ++c) {
            float2 v = make_float2(e[0][c], e[1][c]);
            *(float2*)(EhpT + ((size_t)((b << 8) + c0 + c)) * NP + jloc + (rg << 1)) = v;
        }
    } else {
        float* O = (kind == 0) ? Ehd : (kind == 1) ? Efd : Efp;
#pragma unroll
        for (int r = 0; r < 2; ++r) {
            float4* dst = (float4*)(O + (size_t)(row0 + (rg << 1) + r) * HID + c0);
            dst[0] = make_float4(e[r][0], e[r][1], e[r][2], e[r][3]);
            dst[1] = make_float4(e[r][4], e[r][5], e[r][6], e[r][7]);
        }
    }
}

// K2: shifted scores S[b,i,j] = -2 * sum_h w_h * rcp(1 + Ehd*EhpT).
// No LDS, no barrier. Block = 8 i x 64 j; thread: jg = t&63 (coalesced j),
// iq = t>>6 wave-uniform -> Ehd/w loads are scalar. grid = 8*8*16 = 1024.
__global__ __launch_bounds__(256) void k_scores(
    const float* __restrict__ Ehd, const float* __restrict__ EhpT,
    const float* __restrict__ wsc, float* __restrict__ S) {
    int blk = blockIdx.x;
    int b = blk >> 7, r = blk & 127, it = r >> 4, jt = r & 15;
    int i0 = it * 8, j0 = jt * 64;
    int t = threadIdx.x;
    int jg = t & 63, iq = t >> 6;
    int i = i0 + iq * 2;
    const float4* h0v4 = (const float4*)(Ehd + ((b * ND + i) << 8));
    const float4* h1v4 = (const float4*)(Ehd + ((b * ND + i + 1) << 8));
    const float4* w4   = (const float4*)wsc;
    const float* pT = EhpT + ((size_t)(b << 8)) * NP + j0 + jg;
    float acc0 = 0.f, acc1 = 0.f;
#pragma unroll 4
    for (int h4 = 0; h4 < 64; ++h4) {
        float4 h0 = h0v4[h4];           // wave-uniform (scalar)
        float4 h1 = h1v4[h4];
        float4 wv = w4[h4];
        float p0 = pT[(h4 * 4 + 0) * NP];   // coalesced 256B
        float p1 = pT[(h4 * 4 + 1) * NP];
        float p2 = pT[(h4 * 4 + 2) * NP];
        float p3 = pT[(h4 * 4 + 3) * NP];
        acc0 = fmaf(wv.x, __builtin_amdgcn_rcpf(fmaf(h0.x, p0, 1.f)), acc0);
        acc0 = fmaf(wv.y, __builtin_amdgcn_rcpf(fmaf(h0.y, p1, 1.f)), acc0);
        acc0 = fmaf(wv.z, __builtin_amdgcn_rcpf(fmaf(h0.z, p2, 1.f)), acc0);
        acc0 = fmaf(wv.w, __builtin_amdgcn_rcpf(fmaf(h0.w, p3, 1.f)), acc0);
        acc1 = fmaf(wv.x, __builtin_amdgcn_rcpf(fmaf(h1.x, p0, 1.f)), acc1);
        acc1 = fmaf(wv.y, __builtin_amdgcn_rcpf(fmaf(h1.y, p1, 1.f)), acc1);
        acc1 = fmaf(wv.z, __builtin_amdgcn_rcpf(fmaf(h1.z, p2, 1.f)), acc1);
        acc1 = fmaf(wv.w, __builtin_amdgcn_rcpf(fmaf(h1.w, p3, 1.f)), acc1);
    }
    int base = ((b * ND + i) << 10) + j0 + jg;
    S[base]        = -2.f * acc0;
    S[base + 1024] = -2.f * acc1;
}

// K3: softmax over j per (b,i) row, in place; writes A2 = -2*A.
// No max pass: |S| <= 2*sum|w| <= 32, exp2 arg <= ~46 -> fp32-safe.
__global__ __launch_bounds__(256) void k_softmax(float* __restrict__ S) {
    int row = blockIdx.x;
    int t = threadIdx.x;
    float* Srow = S + (row << 10);
    float4 v = ((float4*)Srow)[t];
    const float L2E = 1.4426950408889634f;
    v.x = __builtin_amdgcn_exp2f(v.x * L2E);
    v.y = __builtin_amdgcn_exp2f(v.y * L2E);
    v.z = __builtin_amdgcn_exp2f(v.z * L2E);
    v.w = __builtin_amdgcn_exp2f(v.w * L2E);
    float s4 = (v.x + v.y) + (v.z + v.w);
#pragma unroll
    for (int off = 32; off > 0; off >>= 1) s4 += __shfl_xor(s4, off, 64);
    __shared__ float wsum[4];
    if ((t & 63) == 0) wsum[t >> 6] = s4;
    __syncthreads();
    float tot = (wsum[0] + wsum[1]) + (wsum[2] + wsum[3]);
    float sneg = -2.0f * __builtin_amdgcn_rcpf(tot);   // A2 = -2*A
    v.x *= sneg; v.y *= sneg; v.z *= sneg; v.w *= sneg;
    ((float4*)Srow)[t] = v;
}

// K4: partial[blk][o] = sum_{i in 32, j in 16} A2 * rcp(1 + Efd*Efp).
// (X_int = 64 + sum of all partials, since sum_j A = 1 per i.)
// Efd from L2 (coalesced 1 KB/wave loads); LDS = 6 KB. grid = 1024.
__global__ __launch_bounds__(256) void k_facc(
    const float* __restrict__ Efd, const float* __restrict__ Efp,
    const float* __restrict__ A2, float* __restrict__ part) {
    int blk = blockIdx.x;
    int b = blk >> 7, rr = blk & 127, ih = rr >> 6, jt = rr & 63;
    int i0 = ih * 32, j0 = jt * 16;
    int t = threadIdx.x;
    __shared__ float4 as4[32 * 4];    // 2 KB  (A2 tile [32 i][16 j])
    __shared__ float4 red[256];       // 4 KB
    if (t < 128) {
        int ii = t >> 2, jq = t & 3;
        as4[t] = ((const float4*)A2)[((b * ND + i0 + ii) << 8) + (j0 >> 2) + jq];
    }
    __syncthreads();

    int o4 = t & 63, jq = t >> 6;
    const float4* fdg = (const float4*)(Efd + ((b * ND + i0) << 8));
    const float4* fpg = (const float4*)(Efp + ((b * NP + j0 + (jq << 2)) << 8));
    float4 fv0 = fpg[o4], fv1 = fpg[64 + o4], fv2 = fpg[128 + o4], fv3 = fpg[192 + o4];
    float4 acc = {0.f, 0.f, 0.f, 0.f};
    for (int i = 0; i < 32; ++i) {
        float4 dv = fdg[(i << 6) + o4];   // global, coalesced, L2-hit
        float4 a  = as4[(i << 2) + jq];
        acc.x = fmaf(a.x, __builtin_amdgcn_rcpf(fmaf(dv.x, fv0.x, 1.f)), acc.x);
        acc.y = fmaf(a.x, __builtin_amdgcn_rcpf(fmaf(dv.y, fv0.y, 1.f)), acc.y);
        acc.z = fmaf(a.x, __builtin_amdgcn_rcpf(fmaf(dv.z, fv0.z, 1.f)), acc.z);
        acc.w = fmaf(a.x, __builtin_amdgcn_rcpf(fmaf(dv.w, fv0.w, 1.f)), acc.w);
        acc.x = fmaf(a.y, __builtin_amdgcn_rcpf(fmaf(dv.x, fv1.x, 1.f)), acc.x);
        acc.y = fmaf(a.y, __builtin_amdgcn_rcpf(fmaf(dv.y, fv1.y, 1.f)), acc.y);
        acc.z = fmaf(a.y, __builtin_amdgcn_rcpf(fmaf(dv.z, fv1.z, 1.f)), acc.z);
        acc.w = fmaf(a.y, __builtin_amdgcn_rcpf(fmaf(dv.w, fv1.w, 1.f)), acc.w);
        acc.x = fmaf(a.z, __builtin_amdgcn_rcpf(fmaf(dv.x, fv2.x, 1.f)), acc.x);
        acc.y = fmaf(a.z, __builtin_amdgcn_rcpf(fmaf(dv.y, fv2.y, 1.f)), acc.y);
        acc.z = fmaf(a.z, __builtin_amdgcn_rcpf(fmaf(dv.z, fv2.z, 1.f)), acc.z);
        acc.w = fmaf(a.z, __builtin_amdgcn_rcpf(fmaf(dv.w, fv2.w, 1.f)), acc.w);
        acc.x = fmaf(a.w, __builtin_amdgcn_rcpf(fmaf(dv.x, fv3.x, 1.f)), acc.x);
        acc.y = fmaf(a.w, __builtin_amdgcn_rcpf(fmaf(dv.y, fv3.y, 1.f)), acc.y);
        acc.z = fmaf(a.w, __builtin_amdgcn_rcpf(fmaf(dv.z, fv3.z, 1.f)), acc.z);
        acc.w = fmaf(a.w, __builtin_amdgcn_rcpf(fmaf(dv.w, fv3.w, 1.f)), acc.w);
    }
    red[t] = acc; __syncthreads();
    if (t < 64) {
        float4 r0 = red[t], r1 = red[64 + t], r2 = red[128 + t], r3 = red[192 + t];
        float4 s;
        s.x = (r0.x + r1.x) + (r2.x + r3.x);
        s.y = (r0.y + r1.y) + (r2.y + r3.y);
        s.z = (r0.z + r1.z) + (r2.z + r3.z);
        s.w = (r0.w + r1.w) + (r2.w + r3.w);
        ((float4*)part)[(blk << 6) + t] = s;
    }
}

// K5: out[b][o] = 64 + sum over 128 partials. 64 blocks (8b x 8 o-chunks).
__global__ __launch_bounds__(256) void k_reduce(
    const float* __restrict__ part, float* __restrict__ out) {
    int b = blockIdx.x >> 3, oc = blockIdx.x & 7;
    int t = threadIdx.x;
    int o = oc * 32 + (t & 31), q0 = t >> 5;
    float s = 0.f;
#pragma unroll
    for (int k = 0; k < 16; ++k)
        s += part[((b * 128 + q0 + k * 8) << 8) + o];
    __shared__ float red[256];
    red[t] = s; __syncthreads();
    for (int st = 128; st >= 32; st >>= 1) {
        if (t < st) red[t] += red[t + st];
        __syncthreads();
    }
    if (t < 32) out[(b << 8) + oc * 32 + t] = 64.0f + red[t];
}

extern "C" void kernel_launch(void* const* d_in, const int* in_sizes, int n_in,
                              void* d_out, int out_size, void* d_ws, size_t ws_size,
                              hipStream_t stream) {
    const float* Xd  = (const float*)d_in[0];
    const float* Xp  = (const float*)d_in[1];
    const float* Wd  = (const float*)d_in[2];
    const float* Wp  = (const float*)d_in[3];
    const float* Wa  = (const float*)d_in[4];
    const float* Wb  = (const float*)d_in[5];
    const float* wsc = (const float*)d_in[6];
    float* out = (float*)d_out;

    float* ws = (float*)d_ws;
    float* Ehd  = ws;                       // 131072
    float* Efd  = Ehd + NB * ND * HID;      // 131072
    float* EhpT = Efd + NB * ND * OUTD;     // 2097152  (transposed [b][h][j])
    float* Efp  = EhpT + NB * NP * HID;     // 2097152
    float* S    = Efp + NB * NP * OUTD;     // 524288
    float* part = EhpT;                     // overlay: EhpT dead after k_scores

    k_proj   <<<1088, 256, 0, stream>>>(Xd, Xp, Wd, Wa, Wp, Wb, Ehd, Efd, EhpT, Efp);
    k_scores <<<1024, 256, 0, stream>>>(Ehd, EhpT, wsc, S);
    k_softmax<<<NB * ND, 256, 0, stream>>>(S);
    k_facc   <<<NB * 128, 256, 0, stream>>>(Efd, Efp, S, part);
    k_reduce <<<64, 256, 0, stream>>>(part, out);
}

// Round 13
// 72.381 us; speedup vs baseline: 2.7499x; 1.4378x over previous
//
#include <hip/hip_runtime.h>

#define NB   8
#define ND   64
#define NP   1024
#define KDIM 128
#define HID  256
#define OUTD 256
#define CSC  2.885390081777927f   // 2*log2(e)

typedef __attribute__((ext_vector_type(8))) short  bf16x8;   // 8 bf16 = 4 VGPR
typedef __attribute__((ext_vector_type(4))) float  f32x4;

// E-trick: E = exp2(CSC*proj) = e^{2*proj};
// sigma = 1/(1 + Ed*Ep) = rcp(fma(Ed,Ep,1));  tanh(xd+xp) = 1 - 2*sigma.
// EhpT stored transposed [b][h][j] -> coalesced j-reads in k_scores.
// Projection GEMM runs on MFMA (bf16 inputs, fp32 accum): fp32 VALU versions
// were operand-delivery-bound at 43-153us (R7-R12); matrix cores amortize
// operands in HW. bf16 adds ~0.02-0.04 abs err (threshold 0.2625, margin 8x).

__device__ __forceinline__ ushort f2bf(float f) {   // round-to-nearest-even
    unsigned u = __float_as_uint(f);
    unsigned r = (u + 0x7FFFu + ((u >> 16) & 1u)) >> 16;
    return (ushort)r;
}

// K0: cast X to bf16 (same layout, k-contig) and W to bf16 TRANSPOSED
// (WT[n][k], k-contig) so both MFMA operands load as single ushort8 frags.
// blocks: [0,1024) Xp; [1024,1088) Xd; [1088,1216) W transpose (32/mat).
__global__ __launch_bounds__(256) void k_cast(
    const float* __restrict__ Xd, const float* __restrict__ Xp,
    const float* __restrict__ Wd, const float* __restrict__ Wa,
    const float* __restrict__ Wp, const float* __restrict__ Wb,
    ushort* __restrict__ Xdbf, ushort* __restrict__ Xpbf,
    ushort* __restrict__ WdT, ushort* __restrict__ WaT,
    ushort* __restrict__ WpT, ushort* __restrict__ WbT) {
    int blk = blockIdx.x, t = threadIdx.x;
    if (blk < 1024) {
        size_t i = ((size_t)blk << 10) + ((size_t)t << 2);
        float4 v = *(const float4*)(Xp + i);
        ushort4 o; o.x = f2bf(v.x); o.y = f2bf(v.y); o.z = f2bf(v.z); o.w = f2bf(v.w);
        *(ushort4*)(Xpbf + i) = o;
    } else if (blk < 1088) {
        size_t i = ((size_t)(blk - 1024) << 10) + ((size_t)t << 2);
        float4 v = *(const float4*)(Xd + i);
        ushort4 o; o.x = f2bf(v.x); o.y = f2bf(v.y); o.z = f2bf(v.z); o.w = f2bf(v.w);
        *(ushort4*)(Xdbf + i) = o;
    } else {
        int r = blk - 1088, mat = r >> 5;
        const float* W = (mat == 0) ? Wd : (mat == 1) ? Wa : (mat == 2) ? Wp : Wb;
        ushort* WT = (mat == 0) ? WdT : (mat == 1) ? WaT : (mat == 2) ? WpT : WbT;
        int o0 = ((r & 31) << 10) + (t << 2);     // output idx = n*128 + k
        int n = o0 >> 7, k0 = o0 & 127;
        ushort4 o;
        o.x = f2bf(W[(k0 + 0) * HID + n]);
        o.y = f2bf(W[(k0 + 1) * HID + n]);
        o.z = f2bf(W[(k0 + 2) * HID + n]);
        o.w = f2bf(W[(k0 + 3) * HID + n]);
        *(ushort4*)(WT + o0) = o;
    }
}

// K1: MFMA projection GEMM + fused exp2. C[m][n] = sum_k A[m][k]*B[n][k]
// (both operands k-contiguous rows of 128). Block tile 64x64, 4 waves 2x2,
// each wave 32x32 via 2x2 16x16x32 frags, K in 4 steps. No LDS.
// Frag layouts (gfx950, m89-verified C/D): A/B lane l half j ->
// row/col l&15, k (l>>4)*8+j. D: col n = l&15, row m = (l>>4)*4 + reg.
// blocks: [0,512) Efp; [512,1024) EhpT (transposed gemm: A=WpT, B=Xp[b]);
// [1024,1056) Ehd; [1056,1088) Efd.
__global__ __launch_bounds__(256) void k_proj_mfma(
    const ushort* __restrict__ Xpbf, const ushort* __restrict__ Xdbf,
    const ushort* __restrict__ WdT, const ushort* __restrict__ WaT,
    const ushort* __restrict__ WpT, const ushort* __restrict__ WbT,
    float* __restrict__ Ehd, float* __restrict__ Efd,
    float* __restrict__ EhpT, float* __restrict__ Efp) {
    int blk = blockIdx.x, t = threadIdx.x;
    const ushort *A, *B;
    float* out; size_t obase; int ostride, am0, bn0;
    if (blk < 512) {                       // Efp[row][o] = Xp . WbT
        int mt = blk >> 2, nt = blk & 3;
        A = Xpbf; am0 = mt * 64; B = WbT; bn0 = nt * 64;
        out = Efp; obase = (size_t)am0 * HID + bn0; ostride = HID;
    } else if (blk < 1024) {               // EhpT[b][h][j] = WpT . Xp[b]
        int r = blk - 512, b = r >> 6, rr = r & 63;
        int mt = rr >> 4, nt = rr & 15;
        A = WpT; am0 = mt * 64;
        B = Xpbf + (size_t)b * NP * KDIM; bn0 = nt * 64;
        out = EhpT; obase = ((size_t)(b * 256 + am0)) * NP + bn0; ostride = NP;
    } else if (blk < 1056) {               // Ehd
        int r = blk - 1024; int mt = r >> 2, nt = r & 3;
        A = Xdbf; am0 = mt * 64; B = WdT; bn0 = nt * 64;
        out = Ehd; obase = (size_t)am0 * HID + bn0; ostride = HID;
    } else {                               // Efd
        int r = blk - 1056; int mt = r >> 2, nt = r & 3;
        A = Xdbf; am0 = mt * 64; B = WaT; bn0 = nt * 64;
        out = Efd; obase = (size_t)am0 * HID + bn0; ostride = HID;
    }
    int l = t & 63, w = t >> 6;
    int wm = (w >> 1) << 5, wn = (w & 1) << 5;
    int lr = l & 15, lk = (l >> 4) << 3;
    const ushort* Ab = A + (size_t)(am0 + wm + lr) * KDIM + lk;
    const ushort* Bb = B + (size_t)(bn0 + wn + lr) * KDIM + lk;

    bf16x8 af[2][4], bf[2][4];
#pragma unroll
    for (int f = 0; f < 2; ++f)
#pragma unroll
        for (int ks = 0; ks < 4; ++ks) {
            af[f][ks] = *(const bf16x8*)(Ab + (size_t)(f << 4) * KDIM + (ks << 5));
            bf[f][ks] = *(const bf16x8*)(Bb + (size_t)(f << 4) * KDIM + (ks << 5));
        }

    f32x4 acc[2][2];
#pragma unroll
    for (int mf = 0; mf < 2; ++mf)
#pragma unroll
        for (int nf = 0; nf < 2; ++nf) acc[mf][nf] = (f32x4){0.f, 0.f, 0.f, 0.f};
#pragma unroll
    for (int ks = 0; ks < 4; ++ks)
#pragma unroll
        for (int mf = 0; mf < 2; ++mf)
#pragma unroll
            for (int nf = 0; nf < 2; ++nf)
                acc[mf][nf] = __builtin_amdgcn_mfma_f32_16x16x32_bf16(
                    af[mf][ks], bf[nf][ks], acc[mf][nf], 0, 0, 0);

#pragma unroll
    for (int mf = 0; mf < 2; ++mf)
#pragma unroll
        for (int nf = 0; nf < 2; ++nf)
#pragma unroll
            for (int r = 0; r < 4; ++r) {
                int m = wm + (mf << 4) + ((l >> 4) << 2) + r;
                int n = wn + (nf << 4) + (l & 15);
                out[obase + (size_t)m * ostride + n] =
                    __builtin_amdgcn_exp2f(acc[mf][nf][r] * CSC);
            }
}

// K2: shifted scores S[b,i,j] = -2 * sum_h w_h * rcp(1 + Ehd*EhpT).
__global__ __launch_bounds__(256) void k_scores(
    const float* __restrict__ Ehd, const float* __restrict__ EhpT,
    const float* __restrict__ wsc, float* __restrict__ S) {
    int blk = blockIdx.x;
    int b = blk >> 7, r = blk & 127, it = r >> 4, jt = r & 15;
    int i0 = it * 8, j0 = jt * 64;
    int t = threadIdx.x;
    int jg = t & 63, iq = t >> 6;
    int i = i0 + iq * 2;
    const float4* h0v4 = (const float4*)(Ehd + ((b * ND + i) << 8));
    const float4* h1v4 = (const float4*)(Ehd + ((b * ND + i + 1) << 8));
    const float4* w4   = (const float4*)wsc;
    const float* pT = EhpT + ((size_t)(b << 8)) * NP + j0 + jg;
    float acc0 = 0.f, acc1 = 0.f;
#pragma unroll 4
    for (int h4 = 0; h4 < 64; ++h4) {
        float4 h0 = h0v4[h4];           // wave-uniform (scalar)
        float4 h1 = h1v4[h4];
        float4 wv = w4[h4];
        float p0 = pT[(h4 * 4 + 0) * NP];   // coalesced 256B
        float p1 = pT[(h4 * 4 + 1) * NP];
        float p2 = pT[(h4 * 4 + 2) * NP];
        float p3 = pT[(h4 * 4 + 3) * NP];
        acc0 = fmaf(wv.x, __builtin_amdgcn_rcpf(fmaf(h0.x, p0, 1.f)), acc0);
        acc0 = fmaf(wv.y, __builtin_amdgcn_rcpf(fmaf(h0.y, p1, 1.f)), acc0);
        acc0 = fmaf(wv.z, __builtin_amdgcn_rcpf(fmaf(h0.z, p2, 1.f)), acc0);
        acc0 = fmaf(wv.w, __builtin_amdgcn_rcpf(fmaf(h0.w, p3, 1.f)), acc0);
        acc1 = fmaf(wv.x, __builtin_amdgcn_rcpf(fmaf(h1.x, p0, 1.f)), acc1);
        acc1 = fmaf(wv.y, __builtin_amdgcn_rcpf(fmaf(h1.y, p1, 1.f)), acc1);
        acc1 = fmaf(wv.z, __builtin_amdgcn_rcpf(fmaf(h1.z, p2, 1.f)), acc1);
        acc1 = fmaf(wv.w, __builtin_amdgcn_rcpf(fmaf(h1.w, p3, 1.f)), acc1);
    }
    int base = ((b * ND + i) << 10) + j0 + jg;
    S[base]        = -2.f * acc0;
    S[base + 1024] = -2.f * acc1;
}

// K3: softmax over j per (b,i) row, in place; writes A2 = -2*A.
__global__ __launch_bounds__(256) void k_softmax(float* __restrict__ S) {
    int row = blockIdx.x;
    int t = threadIdx.x;
    float* Srow = S + (row << 10);
    float4 v = ((float4*)Srow)[t];
    const float L2E = 1.4426950408889634f;
    v.x = __builtin_amdgcn_exp2f(v.x * L2E);
    v.y = __builtin_amdgcn_exp2f(v.y * L2E);
    v.z = __builtin_amdgcn_exp2f(v.z * L2E);
    v.w = __builtin_amdgcn_exp2f(v.w * L2E);
    float s4 = (v.x + v.y) + (v.z + v.w);
#pragma unroll
    for (int off = 32; off > 0; off >>= 1) s4 += __shfl_xor(s4, off, 64);
    __shared__ float wsum[4];
    if ((t & 63) == 0) wsum[t >> 6] = s4;
    __syncthreads();
    float tot = (wsum[0] + wsum[1]) + (wsum[2] + wsum[3]);
    float sneg = -2.0f * __builtin_amdgcn_rcpf(tot);   // A2 = -2*A
    v.x *= sneg; v.y *= sneg; v.z *= sneg; v.w *= sneg;
    ((float4*)Srow)[t] = v;
}

// K4: partial[blk][o] = sum_{i in 32, j in 16} A2 * rcp(1 + Efd*Efp).
__global__ __launch_bounds__(256) void k_facc(
    const float* __restrict__ Efd, const float* __restrict__ Efp,
    const float* __restrict__ A2, float* __restrict__ part) {
    int blk = blockIdx.x;
    int b = blk >> 7, rr = blk & 127, ih = rr >> 6, jt = rr & 63;
    int i0 = ih * 32, j0 = jt * 16;
    int t = threadIdx.x;
    __shared__ float4 as4[32 * 4];
    __shared__ float4 red[256];
    if (t < 128) {
        int ii = t >> 2, jq = t & 3;
        as4[t] = ((const float4*)A2)[((b * ND + i0 + ii) << 8) + (j0 >> 2) + jq];
    }
    __syncthreads();

    int o4 = t & 63, jq = t >> 6;
    const float4* fdg = (const float4*)(Efd + ((b * ND + i0) << 8));
    const float4* fpg = (const float4*)(Efp + ((b * NP + j0 + (jq << 2)) << 8));
    float4 fv0 = fpg[o4], fv1 = fpg[64 + o4], fv2 = fpg[128 + o4], fv3 = fpg[192 + o4];
    float4 acc = {0.f, 0.f, 0.f, 0.f};
    for (int i = 0; i < 32; ++i) {
        float4 dv = fdg[(i << 6) + o4];
        float4 a  = as4[(i << 2) + jq];
        acc.x = fmaf(a.x, __builtin_amdgcn_rcpf(fmaf(dv.x, fv0.x, 1.f)), acc.x);
        acc.y = fmaf(a.x, __builtin_amdgcn_rcpf(fmaf(dv.y, fv0.y, 1.f)), acc.y);
        acc.z = fmaf(a.x, __builtin_amdgcn_rcpf(fmaf(dv.z, fv0.z, 1.f)), acc.z);
        acc.w = fmaf(a.x, __builtin_amdgcn_rcpf(fmaf(dv.w, fv0.w, 1.f)), acc.w);
        acc.x = fmaf(a.y, __builtin_amdgcn_rcpf(fmaf(dv.x, fv1.x, 1.f)), acc.x);
        acc.y = fmaf(a.y, __builtin_amdgcn_rcpf(fmaf(dv.y, fv1.y, 1.f)), acc.y);
        acc.z = fmaf(a.y, __builtin_amdgcn_rcpf(fmaf(dv.z, fv1.z, 1.f)), acc.z);
        acc.w = fmaf(a.y, __builtin_amdgcn_rcpf(fmaf(dv.w, fv1.w, 1.f)), acc.w);
        acc.x = fmaf(a.z, __builtin_amdgcn_rcpf(fmaf(dv.x, fv2.x, 1.f)), acc.x);
        acc.y = fmaf(a.z, __builtin_amdgcn_rcpf(fmaf(dv.y, fv2.y, 1.f)), acc.y);
        acc.z = fmaf(a.z, __builtin_amdgcn_rcpf(fmaf(dv.z, fv2.z, 1.f)), acc.z);
        acc.w = fmaf(a.z, __builtin_amdgcn_rcpf(fmaf(dv.w, fv2.w, 1.f)), acc.w);
        acc.x = fmaf(a.w, __builtin_amdgcn_rcpf(fmaf(dv.x, fv3.x, 1.f)), acc.x);
        acc.y = fmaf(a.w, __builtin_amdgcn_rcpf(fmaf(dv.y, fv3.y, 1.f)), acc.y);
        acc.z = fmaf(a.w, __builtin_amdgcn_rcpf(fmaf(dv.z, fv3.z, 1.f)), acc.z);
        acc.w = fmaf(a.w, __builtin_amdgcn_rcpf(fmaf(dv.w, fv3.w, 1.f)), acc.w);
    }
    red[t] = acc; __syncthreads();
    if (t < 64) {
        float4 r0 = red[t], r1 = red[64 + t], r2 = red[128 + t], r3 = red[192 + t];
        float4 s;
        s.x = (r0.x + r1.x) + (r2.x + r3.x);
        s.y = (r0.y + r1.y) + (r2.y + r3.y);
        s.z = (r0.z + r1.z) + (r2.z + r3.z);
        s.w = (r0.w + r1.w) + (r2.w + r3.w);
        ((float4*)part)[(blk << 6) + t] = s;
    }
}

// K5: out[b][o] = 64 + sum over 128 partials. 64 blocks (8b x 8 o-chunks).
__global__ __launch_bounds__(256) void k_reduce(
    const float* __restrict__ part, float* __restrict__ out) {
    int b = blockIdx.x >> 3, oc = blockIdx.x & 7;
    int t = threadIdx.x;
    int o = oc * 32 + (t & 31), q0 = t >> 5;
    float s = 0.f;
#pragma unroll
    for (int k = 0; k < 16; ++k)
        s += part[((b * 128 + q0 + k * 8) << 8) + o];
    __shared__ float red[256];
    red[t] = s; __syncthreads();
    for (int st = 128; st >= 32; st >>= 1) {
        if (t < st) red[t] += red[t + st];
        __syncthreads();
    }
    if (t < 32) out[(b << 8) + oc * 32 + t] = 64.0f + red[t];
}

extern "C" void kernel_launch(void* const* d_in, const int* in_sizes, int n_in,
                              void* d_out, int out_size, void* d_ws, size_t ws_size,
                              hipStream_t stream) {
    const float* Xd  = (const float*)d_in[0];
    const float* Xp  = (const float*)d_in[1];
    const float* Wd  = (const float*)d_in[2];
    const float* Wp  = (const float*)d_in[3];
    const float* Wa  = (const float*)d_in[4];
    const float* Wb  = (const float*)d_in[5];
    const float* wsc = (const float*)d_in[6];
    float* out = (float*)d_out;

    float* ws = (float*)d_ws;
    float* Ehd  = ws;                       // 131072 f
    float* Efd  = Ehd + NB * ND * HID;      // 131072 f
    float* EhpT = Efd + NB * ND * OUTD;     // 2097152 f  ([b][h][j])
    float* Efp  = EhpT + NB * NP * HID;     // 2097152 f
    float* S    = Efp + NB * NP * OUTD;     // 524288 f
    // bf16 staging: Xpbf overlays S exactly (2 MB; S written later by k_scores)
    ushort* Xpbf = (ushort*)S;              // 1048576 us
    ushort* Xdbf = (ushort*)(S + NB * ND * NP);  // after S: 65536 us
    ushort* WdT  = Xdbf + 65536;            // 32768 us each
    ushort* WaT  = WdT + 32768;
    ushort* WpT  = WaT + 32768;
    ushort* WbT  = WpT + 32768;
    float* part  = EhpT;                    // overlay: EhpT dead after k_scores

    k_cast     <<<1216, 256, 0, stream>>>(Xd, Xp, Wd, Wa, Wp, Wb,
                                          Xdbf, Xpbf, WdT, WaT, WpT, WbT);
    k_proj_mfma<<<1088, 256, 0, stream>>>(Xpbf, Xdbf, WdT, WaT, WpT, WbT,
                                          Ehd, Efd, EhpT, Efp);
    k_scores   <<<1024, 256, 0, stream>>>(Ehd, EhpT, wsc, S);
    k_softmax  <<<NB * ND, 256, 0, stream>>>(S);
    k_facc     <<<NB * 128, 256, 0, stream>>>(Efd, Efp, S, part);
    k_reduce   <<<64, 256, 0, stream>>>(part, out);
}

// Round 14
// 71.736 us; speedup vs baseline: 2.7747x; 1.0090x over previous
//
#include <hip/hip_runtime.h>

#define NB   8
#define ND   64
#define NP   1024
#define KDIM 128
#define HID  256
#define OUTD 256
#define CSC  2.885390081777927f   // 2*log2(e)

typedef __attribute__((ext_vector_type(8))) short  bf16x8;
typedef __attribute__((ext_vector_type(4))) float  f32x4;

// E-trick: E = exp2(CSC*proj) = e^{2*proj};
// sigma = 1/(1+Ed*Ep) = rcp(fma(Ed,Ep,1));  tanh = 1 - 2*sigma.
// EhpT transposed [b][h][j]. Projection on MFMA bf16 (R13: fp32 VALU GEMM was
// operand-delivery-bound). scores+softmax+facc fused per (b,i) row: kills the
// 8MB S round-trip, 2 launches, and the softmax kernel.

__device__ __forceinline__ ushort f2bf(float f) {
    unsigned u = __float_as_uint(f);
    return (ushort)((u + 0x7FFFu + ((u >> 16) & 1u)) >> 16);
}

// K0: cast X -> bf16 (k-contig); W -> bf16 TRANSPOSED (WT[n][k]).
__global__ __launch_bounds__(256) void k_cast(
    const float* __restrict__ Xd, const float* __restrict__ Xp,
    const float* __restrict__ Wd, const float* __restrict__ Wa,
    const float* __restrict__ Wp, const float* __restrict__ Wb,
    ushort* __restrict__ Xdbf, ushort* __restrict__ Xpbf,
    ushort* __restrict__ WdT, ushort* __restrict__ WaT,
    ushort* __restrict__ WpT, ushort* __restrict__ WbT) {
    int blk = blockIdx.x, t = threadIdx.x;
    if (blk < 1024) {
        size_t i = ((size_t)blk << 10) + ((size_t)t << 2);
        float4 v = *(const float4*)(Xp + i);
        ushort4 o; o.x = f2bf(v.x); o.y = f2bf(v.y); o.z = f2bf(v.z); o.w = f2bf(v.w);
        *(ushort4*)(Xpbf + i) = o;
    } else if (blk < 1088) {
        size_t i = ((size_t)(blk - 1024) << 10) + ((size_t)t << 2);
        float4 v = *(const float4*)(Xd + i);
        ushort4 o; o.x = f2bf(v.x); o.y = f2bf(v.y); o.z = f2bf(v.z); o.w = f2bf(v.w);
        *(ushort4*)(Xdbf + i) = o;
    } else {
        int r = blk - 1088, mat = r >> 5;
        const float* W = (mat == 0) ? Wd : (mat == 1) ? Wa : (mat == 2) ? Wp : Wb;
        ushort* WT = (mat == 0) ? WdT : (mat == 1) ? WaT : (mat == 2) ? WpT : WbT;
        int o0 = ((r & 31) << 10) + (t << 2);
        int n = o0 >> 7, k0 = o0 & 127;
        ushort4 o;
        o.x = f2bf(W[(k0 + 0) * HID + n]);
        o.y = f2bf(W[(k0 + 1) * HID + n]);
        o.z = f2bf(W[(k0 + 2) * HID + n]);
        o.w = f2bf(W[(k0 + 3) * HID + n]);
        *(ushort4*)(WT + o0) = o;
    }
}

// K1: MFMA projection + fused exp2 (unchanged from R13; verified absmax 0.0625).
__global__ __launch_bounds__(256) void k_proj_mfma(
    const ushort* __restrict__ Xpbf, const ushort* __restrict__ Xdbf,
    const ushort* __restrict__ WdT, const ushort* __restrict__ WaT,
    const ushort* __restrict__ WpT, const ushort* __restrict__ WbT,
    float* __restrict__ Ehd, float* __restrict__ Efd,
    float* __restrict__ EhpT, float* __restrict__ Efp) {
    int blk = blockIdx.x, t = threadIdx.x;
    const ushort *A, *B;
    float* out; size_t obase; int ostride, am0, bn0;
    if (blk < 512) {
        int mt = blk >> 2, nt = blk & 3;
        A = Xpbf; am0 = mt * 64; B = WbT; bn0 = nt * 64;
        out = Efp; obase = (size_t)am0 * HID + bn0; ostride = HID;
    } else if (blk < 1024) {
        int r = blk - 512, b = r >> 6, rr = r & 63;
        int mt = rr >> 4, nt = rr & 15;
        A = WpT; am0 = mt * 64;
        B = Xpbf + (size_t)b * NP * KDIM; bn0 = nt * 64;
        out = EhpT; obase = ((size_t)(b * 256 + am0)) * NP + bn0; ostride = NP;
    } else if (blk < 1056) {
        int r = blk - 1024; int mt = r >> 2, nt = r & 3;
        A = Xdbf; am0 = mt * 64; B = WdT; bn0 = nt * 64;
        out = Ehd; obase = (size_t)am0 * HID + bn0; ostride = HID;
    } else {
        int r = blk - 1056; int mt = r >> 2, nt = r & 3;
        A = Xdbf; am0 = mt * 64; B = WaT; bn0 = nt * 64;
        out = Efd; obase = (size_t)am0 * HID + bn0; ostride = HID;
    }
    int l = t & 63, w = t >> 6;
    int wm = (w >> 1) << 5, wn = (w & 1) << 5;
    int lr = l & 15, lk = (l >> 4) << 3;
    const ushort* Ab = A + (size_t)(am0 + wm + lr) * KDIM + lk;
    const ushort* Bb = B + (size_t)(bn0 + wn + lr) * KDIM + lk;

    bf16x8 af[2][4], bfr[2][4];
#pragma unroll
    for (int f = 0; f < 2; ++f)
#pragma unroll
        for (int ks = 0; ks < 4; ++ks) {
            af[f][ks]  = *(const bf16x8*)(Ab + (size_t)(f << 4) * KDIM + (ks << 5));
            bfr[f][ks] = *(const bf16x8*)(Bb + (size_t)(f << 4) * KDIM + (ks << 5));
        }

    f32x4 acc[2][2];
#pragma unroll
    for (int mf = 0; mf < 2; ++mf)
#pragma unroll
        for (int nf = 0; nf < 2; ++nf) acc[mf][nf] = (f32x4){0.f, 0.f, 0.f, 0.f};
#pragma unroll
    for (int ks = 0; ks < 4; ++ks)
#pragma unroll
        for (int mf = 0; mf < 2; ++mf)
#pragma unroll
            for (int nf = 0; nf < 2; ++nf)
                acc[mf][nf] = __builtin_amdgcn_mfma_f32_16x16x32_bf16(
                    af[mf][ks], bfr[nf][ks], acc[mf][nf], 0, 0, 0);

#pragma unroll
    for (int mf = 0; mf < 2; ++mf)
#pragma unroll
        for (int nf = 0; nf < 2; ++nf)
#pragma unroll
            for (int r = 0; r < 4; ++r) {
                int m = wm + (mf << 4) + ((l >> 4) << 2) + r;
                int n = wn + (nf << 4) + (l & 15);
                out[obase + (size_t)m * ostride + n] =
                    __builtin_amdgcn_exp2f(acc[mf][nf][r] * CSC);
            }
}

// K2: FUSED scores+softmax+facc. One block per (b,i) row, 512 threads.
// Phase1: 1024 shifted scores (2 j/thread, coalesced EhpT reads, LDS-staged
// Ehd row + w2). Phase2: exp2 + block sum -> A2 in LDS (never leaves CU).
// Phase3: o = t&255, 512 j each; part[row][o] = sum_j A2_j*sigr(fd*fp).
__global__ __launch_bounds__(512) void k_fused(
    const float* __restrict__ Ehd, const float* __restrict__ EhpT,
    const float* __restrict__ Efd, const float* __restrict__ Efp,
    const float* __restrict__ wsc, float* __restrict__ part) {
    int blk = blockIdx.x;            // b*64 + i
    int b = blk >> 6;
    int t = threadIdx.x;
    __shared__ float4 hs4[64];       // Ehd row, 1 KB
    __shared__ float4 w24[64];       // -2*w, 1 KB
    __shared__ float4 a2v[256];      // A2, 4 KB
    __shared__ float  red[512];      // 2 KB
    if (t < 64) {
        hs4[t] = ((const float4*)(Ehd + ((size_t)blk << 8)))[t];
        float4 wv = ((const float4*)wsc)[t];
        w24[t] = make_float4(-2.f * wv.x, -2.f * wv.y, -2.f * wv.z, -2.f * wv.w);
    }
    __syncthreads();

    // ---- phase 1: shifted scores for j = t and t+512 ----
    const float* pT = EhpT + ((size_t)(b << 8)) * NP + t;
    float acc0 = 0.f, acc1 = 0.f;
    for (int h4 = 0; h4 < 64; ++h4) {
        float4 hv = hs4[h4];                 // LDS broadcast
        float4 wv = w24[h4];
        const float* pb = pT + (size_t)(h4 << 2) * NP;
        float p0 = pb[0],        q0 = pb[512];
        float p1 = pb[NP],       q1 = pb[NP + 512];
        float p2 = pb[2 * NP],   q2 = pb[2 * NP + 512];
        float p3 = pb[3 * NP],   q3 = pb[3 * NP + 512];
        acc0 = fmaf(wv.x, __builtin_amdgcn_rcpf(fmaf(hv.x, p0, 1.f)), acc0);
        acc1 = fmaf(wv.x, __builtin_amdgcn_rcpf(fmaf(hv.x, q0, 1.f)), acc1);
        acc0 = fmaf(wv.y, __builtin_amdgcn_rcpf(fmaf(hv.y, p1, 1.f)), acc0);
        acc1 = fmaf(wv.y, __builtin_amdgcn_rcpf(fmaf(hv.y, q1, 1.f)), acc1);
        acc0 = fmaf(wv.z, __builtin_amdgcn_rcpf(fmaf(hv.z, p2, 1.f)), acc0);
        acc1 = fmaf(wv.z, __builtin_amdgcn_rcpf(fmaf(hv.z, q2, 1.f)), acc1);
        acc0 = fmaf(wv.w, __builtin_amdgcn_rcpf(fmaf(hv.w, p3, 1.f)), acc0);
        acc1 = fmaf(wv.w, __builtin_amdgcn_rcpf(fmaf(hv.w, q3, 1.f)), acc1);
    }

    // ---- phase 2: softmax (no max pass: |S| <= 2*sum|w| ~ 32, fp32-safe) ----
    const float L2E = 1.4426950408889634f;
    float e0 = __builtin_amdgcn_exp2f(acc0 * L2E);
    float e1 = __builtin_amdgcn_exp2f(acc1 * L2E);
    float s4 = e0 + e1;
#pragma unroll
    for (int off = 32; off > 0; off >>= 1) s4 += __shfl_xor(s4, off, 64);
    __shared__ float wsum[8];
    if ((t & 63) == 0) wsum[t >> 6] = s4;
    __syncthreads();
    float tot = ((wsum[0] + wsum[1]) + (wsum[2] + wsum[3])) +
                ((wsum[4] + wsum[5]) + (wsum[6] + wsum[7]));
    float sneg = -2.0f * __builtin_amdgcn_rcpf(tot);   // A2 = -2*A
    float* a2 = (float*)a2v;
    a2[t]       = e0 * sneg;
    a2[t + 512] = e1 * sneg;
    __syncthreads();

    // ---- phase 3: facc. o = t&255, j-half = t>>8 (512 j each) ----
    int o = t & 255, half = t >> 8;
    float fdv = Efd[((size_t)blk << 8) + o];
    const float* fp = Efp + (((size_t)(b * NP + (half << 9))) << 8) + o;
    const float4* ah = a2v + (half << 7);    // 128 float4 = 512 floats
    float accA = 0.f, accB = 0.f;
    for (int j4 = 0; j4 < 128; ++j4) {
        const float* fj = fp + ((size_t)j4 << 10);
        float f0 = fj[0];
        float f1 = fj[256];
        float f2 = fj[512];
        float f3 = fj[768];
        float4 av = ah[j4];
        accA = fmaf(av.x, __builtin_amdgcn_rcpf(fmaf(fdv, f0, 1.f)), accA);
        accB = fmaf(av.y, __builtin_amdgcn_rcpf(fmaf(fdv, f1, 1.f)), accB);
        accA = fmaf(av.z, __builtin_amdgcn_rcpf(fmaf(fdv, f2, 1.f)), accA);
        accB = fmaf(av.w, __builtin_amdgcn_rcpf(fmaf(fdv, f3, 1.f)), accB);
    }
    red[t] = accA + accB;
    __syncthreads();
    if (t < 256)
        part[((size_t)blk << 8) + t] = red[t] + red[t + 256];
}

// K3: out[b][o] = 64 + sum over 64 i-rows. grid = 8, 256 threads.
__global__ __launch_bounds__(256) void k_reduce(
    const float* __restrict__ part, float* __restrict__ out) {
    int b = blockIdx.x, t = threadIdx.x;
    float s = 64.0f;   // sum_i sum_j A_ij * 1
#pragma unroll 8
    for (int i = 0; i < 64; ++i)
        s += part[((size_t)(b * 64 + i) << 8) + t];
    out[(b << 8) + t] = s;
}

extern "C" void kernel_launch(void* const* d_in, const int* in_sizes, int n_in,
                              void* d_out, int out_size, void* d_ws, size_t ws_size,
                              hipStream_t stream) {
    const float* Xd  = (const float*)d_in[0];
    const float* Xp  = (const float*)d_in[1];
    const float* Wd  = (const float*)d_in[2];
    const float* Wp  = (const float*)d_in[3];
    const float* Wa  = (const float*)d_in[4];
    const float* Wb  = (const float*)d_in[5];
    const float* wsc = (const float*)d_in[6];
    float* out = (float*)d_out;

    float* ws = (float*)d_ws;
    float* Ehd  = ws;                       // 131072 f
    float* Efd  = Ehd + NB * ND * HID;      // 131072 f
    float* EhpT = Efd + NB * ND * OUTD;     // 2097152 f  ([b][h][j])
    float* Efp  = EhpT + NB * NP * HID;     // 2097152 f
    float* stage = Efp + NB * NP * OUTD;    // staging region (bf16)
    ushort* Xpbf = (ushort*)stage;          // 1048576 us = 2 MB
    ushort* Xdbf = Xpbf + NB * NP * KDIM;   // 65536 us
    ushort* WdT  = Xdbf + 65536;            // 32768 us each
    ushort* WaT  = WdT + 32768;
    ushort* WpT  = WaT + 32768;
    ushort* WbT  = WpT + 32768;
    float* part  = stage;                   // overlay: stage dead after k_proj_mfma

    k_cast     <<<1216, 256, 0, stream>>>(Xd, Xp, Wd, Wa, Wp, Wb,
                                          Xdbf, Xpbf, WdT, WaT, WpT, WbT);
    k_proj_mfma<<<1088, 256, 0, stream>>>(Xpbf, Xdbf, WdT, WaT, WpT, WbT,
                                          Ehd, Efd, EhpT, Efp);
    k_fused    <<<NB * ND, 512, 0, stream>>>(Ehd, EhpT, Efd, Efp, wsc, part);
    k_reduce   <<<NB, 256, 0, stream>>>(part, out);
}